// Round 2
// baseline (131.149 us; speedup 1.0000x reference)
//
#include <hip/hip_runtime.h>
#include <cstdint>
#include <cstddef>

#define IDIM 192
#define NSAMP 128
#define NRAYS 16384
#define NVOX (IDIM * IDIM * IDIM)   // 7077888

__device__ __forceinline__ uint32_t rotl32(uint32_t x, int r) {
    return (x << r) | (x >> (32 - r));
}

// JAX threefry2x32, key (0,1), partitionable path (jax_threefry_partitionable=True,
// default in modern JAX): count i (< 2^32) is hashed as TF((0,1), (hi=0, lo=i)),
// and the 32-bit draw is the XOR of the two output lanes.
__device__ __forceinline__ uint32_t threefry_bits(uint32_t i) {
    const uint32_t ks0 = 0u;
    const uint32_t ks1 = 1u;
    const uint32_t ks2 = 0x1BD11BDAu ^ ks0 ^ ks1;  // 0x1BD11BDB
    uint32_t x0 = 0u + ks0;   // hi32(count) = 0
    uint32_t x1 = i + ks1;    // lo32(count) = i
#define TF_ROUND(r) { x0 += x1; x1 = rotl32(x1, (r)); x1 ^= x0; }
    TF_ROUND(13) TF_ROUND(15) TF_ROUND(26) TF_ROUND(6)
    x0 += ks1; x1 += ks2 + 1u;
    TF_ROUND(17) TF_ROUND(29) TF_ROUND(16) TF_ROUND(24)
    x0 += ks2; x1 += ks0 + 2u;
    TF_ROUND(13) TF_ROUND(15) TF_ROUND(26) TF_ROUND(6)
    x0 += ks0; x1 += ks1 + 3u;
    TF_ROUND(17) TF_ROUND(29) TF_ROUND(16) TF_ROUND(24)
    x0 += ks1; x1 += ks2 + 4u;
    TF_ROUND(13) TF_ROUND(15) TF_ROUND(26) TF_ROUND(6)
    x0 += ks2; x1 += ks0 + 5u;
#undef TF_ROUND
    return x0 ^ x1;
}

// Pre-reduce grid over 9 channels + pair with opacity: tab[v] = {sum_c grid[v][c], opacity[v]}
__global__ __launch_bounds__(256)
void fuse_kernel(const float* __restrict__ grid, const float* __restrict__ opacity,
                 float2* __restrict__ tab) {
    __shared__ float sh[256 * 9];
    const int base = blockIdx.x * 256;
    const float* gp = grid + (size_t)base * 9;
    #pragma unroll
    for (int i = 0; i < 9; ++i) {
        sh[i * 256 + threadIdx.x] = gp[i * 256 + threadIdx.x];
    }
    __syncthreads();
    const int v = base + threadIdx.x;
    float s = 0.f;
    #pragma unroll
    for (int c = 0; c < 9; ++c) s += sh[threadIdx.x * 9 + c];
    tab[v] = make_float2(s, opacity[v]);
}

template <bool FUSED>
__global__ __launch_bounds__(NSAMP)
void rf_kernel(const float* __restrict__ x, const float* __restrict__ d,
               const float* __restrict__ grid, const float* __restrict__ opacity,
               const float2* __restrict__ tab, float* __restrict__ out) {
    const int r = blockIdx.x;
    const int s = threadIdx.x;

    __shared__ float st[NSAMP];
    __shared__ float wtot[2];
    __shared__ float wsum[2];

    // --- ray setup (redundant per thread; cheap, cached) ---
    const float ox = x[r * 3 + 0], oy = x[r * 3 + 1], oz = x[r * 3 + 2];
    const float dx = d[r * 3 + 0], dy = d[r * 3 + 1], dz = d[r * 3 + 2];
    const float inv_dx = 1.f / dx, inv_dy = 1.f / dy, inv_dz = 1.f / dz;
    const float INF = 7077888.f;  // 192^3
    const float BMAX = (float)(IDIM - 1);

    float tmin = -INF, tmax = INF;
    {
        float t0 = (0.f - ox) * inv_dx, t1 = (BMAX - ox) * inv_dx;
        tmin = fmaxf(tmin, fminf(t0, t1)); tmax = fminf(tmax, fmaxf(t0, t1));
        t0 = (0.f - oy) * inv_dy; t1 = (BMAX - oy) * inv_dy;
        tmin = fmaxf(tmin, fminf(t0, t1)); tmax = fminf(tmax, fmaxf(t0, t1));
        t0 = (0.f - oz) * inv_dz; t1 = (BMAX - oz) * inv_dz;
        tmin = fmaxf(tmin, fminf(t0, t1)); tmax = fminf(tmax, fmaxf(t0, t1));
    }

    // --- JAX-exact uniform sample (partitionable threefry) ---
    const uint32_t i = (uint32_t)(r * NSAMP + s);
    const uint32_t bits = threefry_bits(i);
    float u = __uint_as_float((bits >> 9) | 0x3f800000u) - 1.0f;
    u = fmaxf(0.f, u);
    st[s] = tmin + u * (tmax - tmin);
    __syncthreads();

    // --- bitonic sort of 128 values (ascending) ---
    for (int k = 2; k <= NSAMP; k <<= 1) {
        for (int j = k >> 1; j > 0; j >>= 1) {
            const int ixj = s ^ j;
            if (ixj > s) {
                const float a = st[s], b = st[ixj];
                const bool up = ((s & k) == 0);
                if ((a > b) == up) { st[s] = b; st[ixj] = a; }
            }
            __syncthreads();
        }
    }
    const float ts = st[s];
    const float tn = (s < NSAMP - 1) ? st[s + 1] : ts;

    // --- trilinear interpolation (only first 127 samples are used) ---
    float opv = 0.f, hsv = 0.f;
    if (s < NSAMP - 1) {
        const float px = ox + ts * dx;
        const float py = oy + ts * dy;
        const float pz = oz + ts * dz;
        int ix = (int)floorf(px); ix = ix < 0 ? 0 : (ix > IDIM - 2 ? IDIM - 2 : ix);
        int iy = (int)floorf(py); iy = iy < 0 ? 0 : (iy > IDIM - 2 ? IDIM - 2 : iy);
        int iz = (int)floorf(pz); iz = iz < 0 ? 0 : (iz > IDIM - 2 ? IDIM - 2 : iz);
        const float fx = px - (float)ix;
        const float fy = py - (float)iy;
        const float fz = pz - (float)iz;
        const float wx0 = 1.f - fx, wx1 = fx;
        const float wy0 = 1.f - fy, wy1 = fy;
        const float wz0 = 1.f - fz, wz1 = fz;
        const float w000 = wx0 * wy0 * wz0, w001 = wx0 * wy0 * wz1;
        const float w010 = wx0 * wy1 * wz0, w011 = wx0 * wy1 * wz1;
        const float w100 = wx1 * wy0 * wz0, w101 = wx1 * wy0 * wz1;
        const float w110 = wx1 * wy1 * wz0, w111 = wx1 * wy1 * wz1;
        const int SX = IDIM * IDIM, SY = IDIM;
        const int v000 = (ix * IDIM + iy) * IDIM + iz;

        if (FUSED) {
            const float2 c000 = tab[v000];
            const float2 c001 = tab[v000 + 1];
            const float2 c010 = tab[v000 + SY];
            const float2 c011 = tab[v000 + SY + 1];
            const float2 c100 = tab[v000 + SX];
            const float2 c101 = tab[v000 + SX + 1];
            const float2 c110 = tab[v000 + SX + SY];
            const float2 c111 = tab[v000 + SX + SY + 1];
            hsv = w000 * c000.x + w001 * c001.x + w010 * c010.x + w011 * c011.x +
                  w100 * c100.x + w101 * c101.x + w110 * c110.x + w111 * c111.x;
            opv = w000 * c000.y + w001 * c001.y + w010 * c010.y + w011 * c011.y +
                  w100 * c100.y + w101 * c101.y + w110 * c110.y + w111 * c111.y;
        } else {
            auto gsum = [&](int v) -> float {
                const float* g = grid + (size_t)v * 9;
                float acc = 0.f;
                #pragma unroll
                for (int c = 0; c < 9; ++c) acc += g[c];
                return acc;
            };
            hsv = w000 * gsum(v000) + w001 * gsum(v000 + 1) +
                  w010 * gsum(v000 + SY) + w011 * gsum(v000 + SY + 1) +
                  w100 * gsum(v000 + SX) + w101 * gsum(v000 + SX + 1) +
                  w110 * gsum(v000 + SX + SY) + w111 * gsum(v000 + SX + SY + 1);
            opv = w000 * opacity[v000] + w001 * opacity[v000 + 1] +
                  w010 * opacity[v000 + SY] + w011 * opacity[v000 + SY + 1] +
                  w100 * opacity[v000 + SX] + w101 * opacity[v000 + SX + 1] +
                  w110 * opacity[v000 + SX + SY] + w111 * opacity[v000 + SX + SY + 1];
        }
    }

    // --- compositing: exclusive prefix sum of cur over 127 entries ---
    const float cur = (s < NSAMP - 1) ? (tn - ts) * opv : 0.f;
    float incl = cur;
    #pragma unroll
    for (int off = 1; off < 64; off <<= 1) {
        const float v2 = __shfl_up(incl, off, 64);
        if ((s & 63) >= off) incl += v2;
    }
    if ((s & 63) == 63) wtot[s >> 6] = incl;
    __syncthreads();
    if (s >= 64) incl += wtot[0];
    const float excl = incl - cur;

    float contrib = 0.f;
    if (s < NSAMP - 1) {
        const float color = 1.f / (1.f + expf(-hsv));
        contrib = expf(-excl) * (1.f - expf(-cur)) * color;
    }

    // --- block reduction ---
    #pragma unroll
    for (int off = 32; off > 0; off >>= 1) contrib += __shfl_down(contrib, off, 64);
    if ((s & 63) == 0) wsum[s >> 6] = contrib;
    __syncthreads();
    if (s == 0) out[r] = wsum[0] + wsum[1];
}

extern "C" void kernel_launch(void* const* d_in, const int* in_sizes, int n_in,
                              void* d_out, int out_size, void* d_ws, size_t ws_size,
                              hipStream_t stream) {
    const float* x       = (const float*)d_in[0];
    const float* d       = (const float*)d_in[1];
    const float* grid    = (const float*)d_in[2];
    const float* opacity = (const float*)d_in[3];
    float* out = (float*)d_out;

    const size_t need = (size_t)NVOX * sizeof(float2);
    if (ws_size >= need) {
        fuse_kernel<<<NVOX / 256, 256, 0, stream>>>(grid, opacity, (float2*)d_ws);
        rf_kernel<true><<<NRAYS, NSAMP, 0, stream>>>(x, d, grid, opacity,
                                                     (const float2*)d_ws, out);
    } else {
        rf_kernel<false><<<NRAYS, NSAMP, 0, stream>>>(x, d, grid, opacity,
                                                      nullptr, out);
    }
}

// Round 3
// 112.696 us; speedup vs baseline: 1.1637x; 1.1637x over previous
//
#include <hip/hip_runtime.h>
#include <hip/hip_fp16.h>
#include <cstdint>
#include <cstddef>

#define IDIM 192
#define NSAMP 128
#define NRAYS 16384
#define NVOX (IDIM * IDIM * IDIM)   // 7077888

__device__ __forceinline__ uint32_t rotl32(uint32_t x, int r) {
    return (x << r) | (x >> (32 - r));
}

// JAX threefry2x32, key (0,1), partitionable path: bits(i) = x0 ^ x1 of TF((0,1),(0,i))
__device__ __forceinline__ uint32_t threefry_bits(uint32_t i) {
    const uint32_t ks0 = 0u;
    const uint32_t ks1 = 1u;
    const uint32_t ks2 = 0x1BD11BDAu ^ ks0 ^ ks1;  // 0x1BD11BDB
    uint32_t x0 = 0u + ks0;
    uint32_t x1 = i + ks1;
#define TF_ROUND(r) { x0 += x1; x1 = rotl32(x1, (r)); x1 ^= x0; }
    TF_ROUND(13) TF_ROUND(15) TF_ROUND(26) TF_ROUND(6)
    x0 += ks1; x1 += ks2 + 1u;
    TF_ROUND(17) TF_ROUND(29) TF_ROUND(16) TF_ROUND(24)
    x0 += ks2; x1 += ks0 + 2u;
    TF_ROUND(13) TF_ROUND(15) TF_ROUND(26) TF_ROUND(6)
    x0 += ks0; x1 += ks1 + 3u;
    TF_ROUND(17) TF_ROUND(29) TF_ROUND(16) TF_ROUND(24)
    x0 += ks1; x1 += ks2 + 4u;
    TF_ROUND(13) TF_ROUND(15) TF_ROUND(26) TF_ROUND(6)
    x0 += ks2; x1 += ks0 + 5u;
#undef TF_ROUND
    return x0 ^ x1;
}

// tab[v] = half2{ sum_c grid[v][c], opacity[v] }  (4 B/voxel, 28.3 MB total)
__global__ __launch_bounds__(256)
void fuse_kernel(const float* __restrict__ grid, const float* __restrict__ opacity,
                 __half2* __restrict__ tab) {
    __shared__ float sh[256 * 9];
    const int base = blockIdx.x * 256;
    const float* gp = grid + (size_t)base * 9;
    #pragma unroll
    for (int i = 0; i < 9; ++i) {
        sh[i * 256 + threadIdx.x] = gp[i * 256 + threadIdx.x];
    }
    __syncthreads();
    const int v = base + threadIdx.x;
    float s = 0.f;
    #pragma unroll
    for (int c = 0; c < 9; ++c) s += sh[threadIdx.x * 9 + c];
    tab[v] = __floats2half2_rn(s, opacity[v]);
}

__global__ __launch_bounds__(NSAMP)
void rf_kernel(const float* __restrict__ x, const float* __restrict__ d,
               const __half2* __restrict__ tab, float* __restrict__ out) {
    const int r = blockIdx.x;
    const int s = threadIdx.x;

    __shared__ float sv[NSAMP];   // unsorted samples
    __shared__ float st[NSAMP];   // sorted samples
    __shared__ float wtot[2];
    __shared__ float wsum[2];

    // --- ray setup (broadcast loads) ---
    const float ox = x[r * 3 + 0], oy = x[r * 3 + 1], oz = x[r * 3 + 2];
    const float dx = d[r * 3 + 0], dy = d[r * 3 + 1], dz = d[r * 3 + 2];
    const float inv_dx = 1.f / dx, inv_dy = 1.f / dy, inv_dz = 1.f / dz;
    const float INF = 7077888.f;  // 192^3
    const float BMAX = (float)(IDIM - 1);

    float tmin = -INF, tmax = INF;
    {
        float t0 = (0.f - ox) * inv_dx, t1 = (BMAX - ox) * inv_dx;
        tmin = fmaxf(tmin, fminf(t0, t1)); tmax = fminf(tmax, fmaxf(t0, t1));
        t0 = (0.f - oy) * inv_dy; t1 = (BMAX - oy) * inv_dy;
        tmin = fmaxf(tmin, fminf(t0, t1)); tmax = fminf(tmax, fmaxf(t0, t1));
        t0 = (0.f - oz) * inv_dz; t1 = (BMAX - oz) * inv_dz;
        tmin = fmaxf(tmin, fminf(t0, t1)); tmax = fminf(tmax, fmaxf(t0, t1));
    }

    // --- JAX-exact uniform sample (partitionable threefry) ---
    const uint32_t i = (uint32_t)(r * NSAMP + s);
    const uint32_t bits = threefry_bits(i);
    float u = __uint_as_float((bits >> 9) | 0x3f800000u) - 1.0f;
    u = fmaxf(0.f, u);
    const float vi = tmin + u * (tmax - tmin);
    sv[s] = vi;
    __syncthreads();

    // --- rank sort: rank = #{j: v_j < v_i} + #{j<i: v_j == v_i} ---
    int rank = 0;
    #pragma unroll 4
    for (int j = 0; j < NSAMP; j += 4) {
        const float4 q = *reinterpret_cast<const float4*>(&sv[j]);
        rank += (q.x < vi) | ((q.x == vi) & (j + 0 < s));
        rank += (q.y < vi) | ((q.y == vi) & (j + 1 < s));
        rank += (q.z < vi) | ((q.z == vi) & (j + 2 < s));
        rank += (q.w < vi) | ((q.w == vi) & (j + 3 < s));
    }
    st[rank] = vi;
    __syncthreads();
    const float ts = st[s];
    const float tn = (s < NSAMP - 1) ? st[s + 1] : ts;

    // --- trilinear interpolation from fused half2 table ---
    float opv = 0.f, hsv = 0.f;
    if (s < NSAMP - 1) {
        const float px = ox + ts * dx;
        const float py = oy + ts * dy;
        const float pz = oz + ts * dz;
        int ix = (int)floorf(px); ix = ix < 0 ? 0 : (ix > IDIM - 2 ? IDIM - 2 : ix);
        int iy = (int)floorf(py); iy = iy < 0 ? 0 : (iy > IDIM - 2 ? IDIM - 2 : iy);
        int iz = (int)floorf(pz); iz = iz < 0 ? 0 : (iz > IDIM - 2 ? IDIM - 2 : iz);
        const float fx = px - (float)ix;
        const float fy = py - (float)iy;
        const float fz = pz - (float)iz;
        const float wx0 = 1.f - fx, wx1 = fx;
        const float wy0 = 1.f - fy, wy1 = fy;
        const float wz0 = 1.f - fz, wz1 = fz;
        const float w000 = wx0 * wy0 * wz0, w001 = wx0 * wy0 * wz1;
        const float w010 = wx0 * wy1 * wz0, w011 = wx0 * wy1 * wz1;
        const float w100 = wx1 * wy0 * wz0, w101 = wx1 * wy0 * wz1;
        const float w110 = wx1 * wy1 * wz0, w111 = wx1 * wy1 * wz1;
        const int SX = IDIM * IDIM, SY = IDIM;
        const int v000 = (ix * IDIM + iy) * IDIM + iz;

        const float2 c000 = __half22float2(tab[v000]);
        const float2 c001 = __half22float2(tab[v000 + 1]);
        const float2 c010 = __half22float2(tab[v000 + SY]);
        const float2 c011 = __half22float2(tab[v000 + SY + 1]);
        const float2 c100 = __half22float2(tab[v000 + SX]);
        const float2 c101 = __half22float2(tab[v000 + SX + 1]);
        const float2 c110 = __half22float2(tab[v000 + SX + SY]);
        const float2 c111 = __half22float2(tab[v000 + SX + SY + 1]);
        hsv = w000 * c000.x + w001 * c001.x + w010 * c010.x + w011 * c011.x +
              w100 * c100.x + w101 * c101.x + w110 * c110.x + w111 * c111.x;
        opv = w000 * c000.y + w001 * c001.y + w010 * c010.y + w011 * c011.y +
              w100 * c100.y + w101 * c101.y + w110 * c110.y + w111 * c111.y;
    }

    // --- compositing: exclusive prefix sum of cur over 127 entries ---
    const float cur = (s < NSAMP - 1) ? (tn - ts) * opv : 0.f;
    float incl = cur;
    #pragma unroll
    for (int off = 1; off < 64; off <<= 1) {
        const float v2 = __shfl_up(incl, off, 64);
        if ((s & 63) >= off) incl += v2;
    }
    if ((s & 63) == 63) wtot[s >> 6] = incl;
    __syncthreads();
    if (s >= 64) incl += wtot[0];
    const float excl = incl - cur;

    float contrib = 0.f;
    if (s < NSAMP - 1) {
        const float color = 1.f / (1.f + expf(-hsv));
        contrib = expf(-excl) * (1.f - expf(-cur)) * color;
    }

    // --- block reduction ---
    #pragma unroll
    for (int off = 32; off > 0; off >>= 1) contrib += __shfl_down(contrib, off, 64);
    if ((s & 63) == 0) wsum[s >> 6] = contrib;
    __syncthreads();
    if (s == 0) out[r] = wsum[0] + wsum[1];
}

extern "C" void kernel_launch(void* const* d_in, const int* in_sizes, int n_in,
                              void* d_out, int out_size, void* d_ws, size_t ws_size,
                              hipStream_t stream) {
    const float* x       = (const float*)d_in[0];
    const float* d       = (const float*)d_in[1];
    const float* grid    = (const float*)d_in[2];
    const float* opacity = (const float*)d_in[3];
    float* out = (float*)d_out;

    fuse_kernel<<<NVOX / 256, 256, 0, stream>>>(grid, opacity, (__half2*)d_ws);
    rf_kernel<<<NRAYS, NSAMP, 0, stream>>>(x, d, (const __half2*)d_ws, out);
}